// Round 1
// baseline (877.561 us; speedup 1.0000x reference)
//
#include <hip/hip_runtime.h>

#define N_NODES 100000
#define N_EDGES 1600000
#define IN_F 256
#define OUT_F 128

// ---------------- kernel 1: masked weight  wm = (mask>0.5)?w:0 ----------------
__global__ void mask_w_kernel(const float* __restrict__ weight,
                              const float* __restrict__ mask_real,
                              float* __restrict__ wm) {
    int i = blockIdx.x * blockDim.x + threadIdx.x;
    if (i < IN_F * OUT_F)
        wm[i] = (mask_real[i] > 0.5f) ? weight[i] : 0.0f;
}

// ---------------- kernel 2: degree counts ----------------
__global__ void deg_kernel(const int* __restrict__ src, const int* __restrict__ dst,
                           unsigned* __restrict__ outdeg, unsigned* __restrict__ indeg) {
    int e = blockIdx.x * blockDim.x + threadIdx.x;
    if (e < N_EDGES) {
        atomicAdd(&outdeg[src[e]], 1u);
        atomicAdd(&indeg[dst[e]], 1u);
    }
}

// ---------------- kernel 3: exclusive scan of indeg -> offsets (and cursor copy) ----------------
__global__ __launch_bounds__(1024) void scan_kernel(const unsigned* __restrict__ indeg,
                                                    unsigned* __restrict__ offsets,
                                                    unsigned* __restrict__ cursor) {
    __shared__ unsigned part[1024];
    int t = threadIdx.x;
    const int chunk = (N_NODES + 1023) / 1024;   // 98
    int start = t * chunk;
    int end = min(start + chunk, N_NODES);
    unsigned s = 0;
    for (int i = start; i < end; i++) s += indeg[i];
    part[t] = s;
    __syncthreads();
    // Hillis-Steele inclusive scan over 1024 partials
    for (int d = 1; d < 1024; d <<= 1) {
        unsigned v = (t >= d) ? part[t - d] : 0u;
        __syncthreads();
        part[t] += v;
        __syncthreads();
    }
    unsigned run = part[t] - s;   // exclusive prefix for this thread's chunk
    for (int i = start; i < end; i++) {
        offsets[i] = run;
        cursor[i] = run;
        run += indeg[i];
    }
    if (start < N_NODES && end == N_NODES) offsets[N_NODES] = run;
}

// ---------------- kernel 4: fill CSR edge index via atomic cursor ----------------
__global__ void fill_kernel(const int* __restrict__ dst,
                            unsigned* __restrict__ cursor,
                            unsigned* __restrict__ eidx) {
    int e = blockIdx.x * blockDim.x + threadIdx.x;
    if (e < N_EDGES) {
        int d = dst[e];
        unsigned pos = atomicAdd(&cursor[d], 1u);
        eidx[pos] = (unsigned)e;
    }
}

// ---------------- kernel 5: fp32 GEMM  h = (feat * outscale) @ wm ----------------
// tile: 32 rows x 128 cols per block, 256 threads, 4x4 register blocking.
#define MT 32
#define KT 64

#define MMA_ROW(R, A)                                   \
    acc[R][0] = fmaf((A).x, b0.x, acc[R][0]);           \
    acc[R][0] = fmaf((A).y, b1.x, acc[R][0]);           \
    acc[R][0] = fmaf((A).z, b2.x, acc[R][0]);           \
    acc[R][0] = fmaf((A).w, b3.x, acc[R][0]);           \
    acc[R][1] = fmaf((A).x, b0.y, acc[R][1]);           \
    acc[R][1] = fmaf((A).y, b1.y, acc[R][1]);           \
    acc[R][1] = fmaf((A).z, b2.y, acc[R][1]);           \
    acc[R][1] = fmaf((A).w, b3.y, acc[R][1]);           \
    acc[R][2] = fmaf((A).x, b0.z, acc[R][2]);           \
    acc[R][2] = fmaf((A).y, b1.z, acc[R][2]);           \
    acc[R][2] = fmaf((A).z, b2.z, acc[R][2]);           \
    acc[R][2] = fmaf((A).w, b3.z, acc[R][2]);           \
    acc[R][3] = fmaf((A).x, b0.w, acc[R][3]);           \
    acc[R][3] = fmaf((A).y, b1.w, acc[R][3]);           \
    acc[R][3] = fmaf((A).z, b2.w, acc[R][3]);           \
    acc[R][3] = fmaf((A).w, b3.w, acc[R][3]);

__global__ __launch_bounds__(256) void gemm_kernel(const float* __restrict__ feat,
                                                   const float* __restrict__ wm,
                                                   const unsigned* __restrict__ outdeg,
                                                   float* __restrict__ h) {
    __shared__ float sA[MT][KT];      // 8 KB, row-major [r][k]
    __shared__ float sB[KT][OUT_F];   // 32 KB, row-major [k][f]
    int t = threadIdx.x;
    int row0 = blockIdx.x * MT;
    int fg = (t & 31) * 4;            // output col group
    int rg = (t >> 5) * 4;            // output row group
    float acc[4][4] = {};

    for (int k0 = 0; k0 < IN_F; k0 += KT) {
        // load A tile: 32 rows x 64 k. 256 threads: 16 f4/row-pair
        {
            int lr = t >> 4;           // 0..15
            int lc = (t & 15) * 4;     // 0..60
            float4 v0 = *(const float4*)&feat[(size_t)(row0 + lr) * IN_F + k0 + lc];
            float4 v1 = *(const float4*)&feat[(size_t)(row0 + lr + 16) * IN_F + k0 + lc];
            *(float4*)&sA[lr][lc] = v0;
            *(float4*)&sA[lr + 16][lc] = v1;
        }
        // load B tile: 64 k x 128 f
        {
            int bk = t >> 5;           // 0..7
            int bf = (t & 31) * 4;
#pragma unroll
            for (int kk = 0; kk < KT; kk += 8) {
                *(float4*)&sB[bk + kk][bf] =
                    *(const float4*)&wm[(size_t)(k0 + bk + kk) * OUT_F + bf];
            }
        }
        __syncthreads();
#pragma unroll
        for (int k = 0; k < KT; k += 4) {
            float4 a0 = *(const float4*)&sA[rg + 0][k];
            float4 a1 = *(const float4*)&sA[rg + 1][k];
            float4 a2 = *(const float4*)&sA[rg + 2][k];
            float4 a3 = *(const float4*)&sA[rg + 3][k];
            float4 b0 = *(const float4*)&sB[k + 0][fg];
            float4 b1 = *(const float4*)&sB[k + 1][fg];
            float4 b2 = *(const float4*)&sB[k + 2][fg];
            float4 b3 = *(const float4*)&sB[k + 3][fg];
            MMA_ROW(0, a0)
            MMA_ROW(1, a1)
            MMA_ROW(2, a2)
            MMA_ROW(3, a3)
        }
        __syncthreads();
    }
    // scale by outdeg^-0.5 (scaling after the dot == scaling feat rows before)
#pragma unroll
    for (int r = 0; r < 4; r++) {
        unsigned dg = outdeg[row0 + rg + r];
        float s = rsqrtf(fmaxf((float)dg, 1.0f));
        float4 o;
        o.x = acc[r][0] * s;
        o.y = acc[r][1] * s;
        o.z = acc[r][2] * s;
        o.w = acc[r][3] * s;
        *(float4*)&h[(size_t)(row0 + rg + r) * OUT_F + fg] = o;
    }
}

// ---------------- kernel 6: CSR gather-sum per dst node ----------------
__global__ __launch_bounds__(128) void gather_kernel(const int* __restrict__ src,
                                                     const float* __restrict__ ew,
                                                     const unsigned* __restrict__ offsets,
                                                     const unsigned* __restrict__ eidx,
                                                     const float* __restrict__ h,
                                                     const float* __restrict__ bias,
                                                     float* __restrict__ out) {
    int n = blockIdx.x;
    int t = threadIdx.x;
    __shared__ int s_src[128];
    __shared__ float s_ew[128];
    unsigned beg = offsets[n], end = offsets[n + 1];
    int deg = (int)(end - beg);
    float acc = 0.0f;
    for (int base = 0; base < deg; base += 128) {
        int c = min(128, deg - base);
        if (t < c) {
            unsigned e = eidx[beg + base + t];
            s_src[t] = src[e];
            s_ew[t] = ew[e];
        }
        __syncthreads();
        int i = 0;
        for (; i + 4 <= c; i += 4) {
            int q0 = s_src[i], q1 = s_src[i + 1], q2 = s_src[i + 2], q3 = s_src[i + 3];
            float w0 = s_ew[i], w1 = s_ew[i + 1], w2 = s_ew[i + 2], w3 = s_ew[i + 3];
            float h0 = h[(size_t)q0 * OUT_F + t];
            float h1 = h[(size_t)q1 * OUT_F + t];
            float h2 = h[(size_t)q2 * OUT_F + t];
            float h3 = h[(size_t)q3 * OUT_F + t];
            acc += h0 * w0 + h1 * w1 + h2 * w2 + h3 * w3;
        }
        for (; i < c; i++)
            acc += h[(size_t)s_src[i] * OUT_F + t] * s_ew[i];
        __syncthreads();
    }
    // in_deg == deg; norm 'both' right scale
    float s = rsqrtf(fmaxf((float)deg, 1.0f));
    out[(size_t)n * OUT_F + t] = acc * s + bias[t];
}

extern "C" void kernel_launch(void* const* d_in, const int* in_sizes, int n_in,
                              void* d_out, int out_size, void* d_ws, size_t ws_size,
                              hipStream_t stream) {
    const float* feat      = (const float*)d_in[0];
    const int*   src       = (const int*)d_in[1];
    const int*   dst       = (const int*)d_in[2];
    const float* ew        = (const float*)d_in[3];
    const float* weight    = (const float*)d_in[4];
    const float* bias      = (const float*)d_in[5];
    const float* mask_real = (const float*)d_in[6];
    float* out = (float*)d_out;

    char* ws = (char*)d_ws;
    size_t o = 0;
    auto take = [&](size_t bytes) {
        char* p = ws + o;
        o = (o + bytes + 255) & ~(size_t)255;
        return p;
    };
    float*    wm     = (float*)take((size_t)IN_F * OUT_F * 4);
    unsigned* outdeg = (unsigned*)take((size_t)N_NODES * 4);
    unsigned* indeg  = (unsigned*)take((size_t)N_NODES * 4);
    unsigned* offs   = (unsigned*)take((size_t)(N_NODES + 1) * 4);
    unsigned* cursor = (unsigned*)take((size_t)N_NODES * 4);
    unsigned* eidx   = (unsigned*)take((size_t)N_EDGES * 4);
    float*    h      = (float*)take((size_t)N_NODES * OUT_F * 4);

    hipMemsetAsync(outdeg, 0, (size_t)N_NODES * 4, stream);
    hipMemsetAsync(indeg, 0, (size_t)N_NODES * 4, stream);

    mask_w_kernel<<<(IN_F * OUT_F + 255) / 256, 256, 0, stream>>>(weight, mask_real, wm);
    deg_kernel<<<(N_EDGES + 255) / 256, 256, 0, stream>>>(src, dst, outdeg, indeg);
    scan_kernel<<<1, 1024, 0, stream>>>(indeg, offs, cursor);
    gemm_kernel<<<N_NODES / MT, 256, 0, stream>>>(feat, wm, outdeg, h);
    fill_kernel<<<(N_EDGES + 255) / 256, 256, 0, stream>>>(dst, cursor, eidx);
    gather_kernel<<<N_NODES, 128, 0, stream>>>(src, ew, offs, eidx, h, bias, out);
}

// Round 2
// 656.310 us; speedup vs baseline: 1.3371x; 1.3371x over previous
//
#include <hip/hip_runtime.h>

#define N_NODES 100000
#define N_EDGES 1600000
#define IN_F 256
#define OUT_F 128
#define SCAN_NB ((N_NODES + 255) / 256)   // 391

// ---------------- kernel 1: masked weight  wm = (mask>0.5)?w:0 ----------------
__global__ void mask_w_kernel(const float* __restrict__ weight,
                              const float* __restrict__ mask_real,
                              float* __restrict__ wm) {
    int i = blockIdx.x * blockDim.x + threadIdx.x;
    if (i < IN_F * OUT_F)
        wm[i] = (mask_real[i] > 0.5f) ? weight[i] : 0.0f;
}

// ---------------- kernel 2: degree counts ----------------
__global__ void deg_kernel(const int* __restrict__ src, const int* __restrict__ dst,
                           unsigned* __restrict__ outdeg, unsigned* __restrict__ indeg) {
    int e = blockIdx.x * blockDim.x + threadIdx.x;
    if (e < N_EDGES) {
        atomicAdd(&outdeg[src[e]], 1u);
        atomicAdd(&indeg[dst[e]], 1u);
    }
}

// ---------------- hierarchical exclusive scan of indeg -> offsets, cursor ----------------
// phase 1: per-block (256-elem chunk) sums
__global__ __launch_bounds__(256) void scan_reduce(const unsigned* __restrict__ indeg,
                                                   unsigned* __restrict__ bsum) {
    __shared__ unsigned red[256];
    int t = threadIdx.x;
    int i = blockIdx.x * 256 + t;
    red[t] = (i < N_NODES) ? indeg[i] : 0u;
    __syncthreads();
#pragma unroll
    for (int d = 128; d > 0; d >>= 1) {
        if (t < d) red[t] += red[t + d];
        __syncthreads();
    }
    if (t == 0) bsum[blockIdx.x] = red[0];
}

// phase 2: single small block scans the 391 block sums -> exclusive block prefixes
__global__ __launch_bounds__(512) void scan_spine(const unsigned* __restrict__ bsum,
                                                  unsigned* __restrict__ bpref,
                                                  unsigned* __restrict__ offsets) {
    __shared__ unsigned part[512];
    int t = threadIdx.x;
    unsigned v = (t < SCAN_NB) ? bsum[t] : 0u;
    part[t] = v;
    __syncthreads();
#pragma unroll
    for (int d = 1; d < 512; d <<= 1) {
        unsigned x = (t >= d) ? part[t - d] : 0u;
        __syncthreads();
        part[t] += x;
        __syncthreads();
    }
    if (t < SCAN_NB) bpref[t] = part[t] - v;   // exclusive
    if (t == 511) offsets[N_NODES] = part[511]; // grand total (pads are 0)
}

// phase 3: per-block local exclusive scan + spine offset
__global__ __launch_bounds__(256) void scan_apply(const unsigned* __restrict__ indeg,
                                                  const unsigned* __restrict__ bpref,
                                                  unsigned* __restrict__ offsets,
                                                  unsigned* __restrict__ cursor) {
    __shared__ unsigned part[256];
    int t = threadIdx.x;
    int i = blockIdx.x * 256 + t;
    unsigned v = (i < N_NODES) ? indeg[i] : 0u;
    part[t] = v;
    __syncthreads();
#pragma unroll
    for (int d = 1; d < 256; d <<= 1) {
        unsigned x = (t >= d) ? part[t - d] : 0u;
        __syncthreads();
        part[t] += x;
        __syncthreads();
    }
    if (i < N_NODES) {
        unsigned off = bpref[blockIdx.x] + part[t] - v;
        offsets[i] = off;
        cursor[i] = off;
    }
}

// ---------------- kernel 4: fill CSR edge index via atomic cursor ----------------
__global__ void fill_kernel(const int* __restrict__ dst,
                            unsigned* __restrict__ cursor,
                            unsigned* __restrict__ eidx) {
    int e = blockIdx.x * blockDim.x + threadIdx.x;
    if (e < N_EDGES) {
        int d = dst[e];
        unsigned pos = atomicAdd(&cursor[d], 1u);
        eidx[pos] = (unsigned)e;
    }
}

// ---------------- kernel 5: fp32 GEMM  h = (feat * outscale) @ wm ----------------
// tile: 32 rows x 128 cols per block, 256 threads, 4x4 register blocking.
#define MT 32
#define KT 64

#define MMA_ROW(R, A)                                   \
    acc[R][0] = fmaf((A).x, b0.x, acc[R][0]);           \
    acc[R][0] = fmaf((A).y, b1.x, acc[R][0]);           \
    acc[R][0] = fmaf((A).z, b2.x, acc[R][0]);           \
    acc[R][0] = fmaf((A).w, b3.x, acc[R][0]);           \
    acc[R][1] = fmaf((A).x, b0.y, acc[R][1]);           \
    acc[R][1] = fmaf((A).y, b1.y, acc[R][1]);           \
    acc[R][1] = fmaf((A).z, b2.y, acc[R][1]);           \
    acc[R][1] = fmaf((A).w, b3.y, acc[R][1]);           \
    acc[R][2] = fmaf((A).x, b0.z, acc[R][2]);           \
    acc[R][2] = fmaf((A).y, b1.z, acc[R][2]);           \
    acc[R][2] = fmaf((A).z, b2.z, acc[R][2]);           \
    acc[R][2] = fmaf((A).w, b3.z, acc[R][2]);           \
    acc[R][3] = fmaf((A).x, b0.w, acc[R][3]);           \
    acc[R][3] = fmaf((A).y, b1.w, acc[R][3]);           \
    acc[R][3] = fmaf((A).z, b2.w, acc[R][3]);           \
    acc[R][3] = fmaf((A).w, b3.w, acc[R][3]);

__global__ __launch_bounds__(256) void gemm_kernel(const float* __restrict__ feat,
                                                   const float* __restrict__ wm,
                                                   const unsigned* __restrict__ outdeg,
                                                   float* __restrict__ h) {
    __shared__ float sA[MT][KT];      // 8 KB, row-major [r][k]
    __shared__ float sB[KT][OUT_F];   // 32 KB, row-major [k][f]
    int t = threadIdx.x;
    int row0 = blockIdx.x * MT;
    int fg = (t & 31) * 4;            // output col group
    int rg = (t >> 5) * 4;            // output row group
    float acc[4][4] = {};

    for (int k0 = 0; k0 < IN_F; k0 += KT) {
        // load A tile: 32 rows x 64 k. 256 threads: 16 f4/row-pair
        {
            int lr = t >> 4;           // 0..15
            int lc = (t & 15) * 4;     // 0..60
            float4 v0 = *(const float4*)&feat[(size_t)(row0 + lr) * IN_F + k0 + lc];
            float4 v1 = *(const float4*)&feat[(size_t)(row0 + lr + 16) * IN_F + k0 + lc];
            *(float4*)&sA[lr][lc] = v0;
            *(float4*)&sA[lr + 16][lc] = v1;
        }
        // load B tile: 64 k x 128 f
        {
            int bk = t >> 5;           // 0..7
            int bf = (t & 31) * 4;
#pragma unroll
            for (int kk = 0; kk < KT; kk += 8) {
                *(float4*)&sB[bk + kk][bf] =
                    *(const float4*)&wm[(size_t)(k0 + bk + kk) * OUT_F + bf];
            }
        }
        __syncthreads();
#pragma unroll
        for (int k = 0; k < KT; k += 4) {
            float4 a0 = *(const float4*)&sA[rg + 0][k];
            float4 a1 = *(const float4*)&sA[rg + 1][k];
            float4 a2 = *(const float4*)&sA[rg + 2][k];
            float4 a3 = *(const float4*)&sA[rg + 3][k];
            float4 b0 = *(const float4*)&sB[k + 0][fg];
            float4 b1 = *(const float4*)&sB[k + 1][fg];
            float4 b2 = *(const float4*)&sB[k + 2][fg];
            float4 b3 = *(const float4*)&sB[k + 3][fg];
            MMA_ROW(0, a0)
            MMA_ROW(1, a1)
            MMA_ROW(2, a2)
            MMA_ROW(3, a3)
        }
        __syncthreads();
    }
    // scale by outdeg^-0.5 (scaling after the dot == scaling feat rows before)
#pragma unroll
    for (int r = 0; r < 4; r++) {
        unsigned dg = outdeg[row0 + rg + r];
        float s = rsqrtf(fmaxf((float)dg, 1.0f));
        float4 o;
        o.x = acc[r][0] * s;
        o.y = acc[r][1] * s;
        o.z = acc[r][2] * s;
        o.w = acc[r][3] * s;
        *(float4*)&h[(size_t)(row0 + rg + r) * OUT_F + fg] = o;
    }
}

// ---------------- kernel 6: CSR gather-sum per dst node ----------------
__global__ __launch_bounds__(128) void gather_kernel(const int* __restrict__ src,
                                                     const float* __restrict__ ew,
                                                     const unsigned* __restrict__ offsets,
                                                     const unsigned* __restrict__ eidx,
                                                     const float* __restrict__ h,
                                                     const float* __restrict__ bias,
                                                     float* __restrict__ out) {
    int n = blockIdx.x;
    int t = threadIdx.x;
    __shared__ int s_src[128];
    __shared__ float s_ew[128];
    unsigned beg = offsets[n], end = offsets[n + 1];
    int deg = (int)(end - beg);
    float acc = 0.0f;
    for (int base = 0; base < deg; base += 128) {
        int c = min(128, deg - base);
        if (t < c) {
            unsigned e = eidx[beg + base + t];
            s_src[t] = src[e];
            s_ew[t] = ew[e];
        }
        __syncthreads();
        int i = 0;
        for (; i + 4 <= c; i += 4) {
            int q0 = s_src[i], q1 = s_src[i + 1], q2 = s_src[i + 2], q3 = s_src[i + 3];
            float w0 = s_ew[i], w1 = s_ew[i + 1], w2 = s_ew[i + 2], w3 = s_ew[i + 3];
            float h0 = h[(size_t)q0 * OUT_F + t];
            float h1 = h[(size_t)q1 * OUT_F + t];
            float h2 = h[(size_t)q2 * OUT_F + t];
            float h3 = h[(size_t)q3 * OUT_F + t];
            acc += h0 * w0 + h1 * w1 + h2 * w2 + h3 * w3;
        }
        for (; i < c; i++)
            acc += h[(size_t)s_src[i] * OUT_F + t] * s_ew[i];
        __syncthreads();
    }
    // in_deg == deg; norm 'both' right scale
    float s = rsqrtf(fmaxf((float)deg, 1.0f));
    out[(size_t)n * OUT_F + t] = acc * s + bias[t];
}

extern "C" void kernel_launch(void* const* d_in, const int* in_sizes, int n_in,
                              void* d_out, int out_size, void* d_ws, size_t ws_size,
                              hipStream_t stream) {
    const float* feat      = (const float*)d_in[0];
    const int*   src       = (const int*)d_in[1];
    const int*   dst       = (const int*)d_in[2];
    const float* ew        = (const float*)d_in[3];
    const float* weight    = (const float*)d_in[4];
    const float* bias      = (const float*)d_in[5];
    const float* mask_real = (const float*)d_in[6];
    float* out = (float*)d_out;

    char* ws = (char*)d_ws;
    size_t o = 0;
    auto take = [&](size_t bytes) {
        char* p = ws + o;
        o = (o + bytes + 255) & ~(size_t)255;
        return p;
    };
    float*    wm     = (float*)take((size_t)IN_F * OUT_F * 4);
    unsigned* outdeg = (unsigned*)take((size_t)N_NODES * 4);
    unsigned* indeg  = (unsigned*)take((size_t)N_NODES * 4);
    unsigned* offs   = (unsigned*)take((size_t)(N_NODES + 1) * 4);
    unsigned* cursor = (unsigned*)take((size_t)N_NODES * 4);
    unsigned* eidx   = (unsigned*)take((size_t)N_EDGES * 4);
    unsigned* bsum   = (unsigned*)take((size_t)SCAN_NB * 4);
    unsigned* bpref  = (unsigned*)take((size_t)SCAN_NB * 4);
    float*    h      = (float*)take((size_t)N_NODES * OUT_F * 4);

    hipMemsetAsync(outdeg, 0, (size_t)N_NODES * 4, stream);
    hipMemsetAsync(indeg, 0, (size_t)N_NODES * 4, stream);

    mask_w_kernel<<<(IN_F * OUT_F + 255) / 256, 256, 0, stream>>>(weight, mask_real, wm);
    deg_kernel<<<(N_EDGES + 255) / 256, 256, 0, stream>>>(src, dst, outdeg, indeg);
    scan_reduce<<<SCAN_NB, 256, 0, stream>>>(indeg, bsum);
    scan_spine<<<1, 512, 0, stream>>>(bsum, bpref, offs);
    scan_apply<<<SCAN_NB, 256, 0, stream>>>(indeg, bpref, offs, cursor);
    gemm_kernel<<<N_NODES / MT, 256, 0, stream>>>(feat, wm, outdeg, h);
    fill_kernel<<<(N_EDGES + 255) / 256, 256, 0, stream>>>(dst, cursor, eidx);
    gather_kernel<<<N_NODES, 128, 0, stream>>>(src, ew, offs, eidx, h, bias, out);
}

// Round 3
// 615.288 us; speedup vs baseline: 1.4263x; 1.0667x over previous
//
#include <hip/hip_runtime.h>

#define N_NODES 100000
#define N_EDGES 1600000
#define IN_F 256
#define OUT_F 128
#define SCAN_NB ((N_NODES + 255) / 256)   // 391

// ---------------- kernel 1: masked weight  wm = (mask>0.5)?w:0 ----------------
__global__ void mask_w_kernel(const float* __restrict__ weight,
                              const float* __restrict__ mask_real,
                              float* __restrict__ wm) {
    int i = blockIdx.x * blockDim.x + threadIdx.x;
    if (i < IN_F * OUT_F)
        wm[i] = (mask_real[i] > 0.5f) ? weight[i] : 0.0f;
}

// ---------------- kernel 2: degree counts ----------------
__global__ void deg_kernel(const int* __restrict__ src, const int* __restrict__ dst,
                           unsigned* __restrict__ outdeg, unsigned* __restrict__ indeg) {
    int e = blockIdx.x * blockDim.x + threadIdx.x;
    if (e < N_EDGES) {
        atomicAdd(&outdeg[src[e]], 1u);
        atomicAdd(&indeg[dst[e]], 1u);
    }
}

// ---------------- hierarchical exclusive scan of indeg -> offsets, cursor ----------------
__global__ __launch_bounds__(256) void scan_reduce(const unsigned* __restrict__ indeg,
                                                   unsigned* __restrict__ bsum) {
    __shared__ unsigned red[256];
    int t = threadIdx.x;
    int i = blockIdx.x * 256 + t;
    red[t] = (i < N_NODES) ? indeg[i] : 0u;
    __syncthreads();
#pragma unroll
    for (int d = 128; d > 0; d >>= 1) {
        if (t < d) red[t] += red[t + d];
        __syncthreads();
    }
    if (t == 0) bsum[blockIdx.x] = red[0];
}

__global__ __launch_bounds__(512) void scan_spine(const unsigned* __restrict__ bsum,
                                                  unsigned* __restrict__ bpref,
                                                  unsigned* __restrict__ offsets) {
    __shared__ unsigned part[512];
    int t = threadIdx.x;
    unsigned v = (t < SCAN_NB) ? bsum[t] : 0u;
    part[t] = v;
    __syncthreads();
#pragma unroll
    for (int d = 1; d < 512; d <<= 1) {
        unsigned x = (t >= d) ? part[t - d] : 0u;
        __syncthreads();
        part[t] += x;
        __syncthreads();
    }
    if (t < SCAN_NB) bpref[t] = part[t] - v;    // exclusive
    if (t == 511) offsets[N_NODES] = part[511]; // grand total
}

__global__ __launch_bounds__(256) void scan_apply(const unsigned* __restrict__ indeg,
                                                  const unsigned* __restrict__ bpref,
                                                  unsigned* __restrict__ offsets,
                                                  unsigned* __restrict__ cursor) {
    __shared__ unsigned part[256];
    int t = threadIdx.x;
    int i = blockIdx.x * 256 + t;
    unsigned v = (i < N_NODES) ? indeg[i] : 0u;
    part[t] = v;
    __syncthreads();
#pragma unroll
    for (int d = 1; d < 256; d <<= 1) {
        unsigned x = (t >= d) ? part[t - d] : 0u;
        __syncthreads();
        part[t] += x;
        __syncthreads();
    }
    if (i < N_NODES) {
        unsigned off = bpref[blockIdx.x] + part[t] - v;
        offsets[i] = off;
        cursor[i] = off;
    }
}

// ---------------- kernel 4: fill CSR with pre-resolved {src, ew} pairs ----------------
__global__ void fill_kernel(const int* __restrict__ src,
                            const int* __restrict__ dst,
                            const float* __restrict__ ew,
                            unsigned* __restrict__ cursor,
                            uint2* __restrict__ smeta) {
    int e = blockIdx.x * blockDim.x + threadIdx.x;
    if (e < N_EDGES) {
        int d = dst[e];
        unsigned pos = atomicAdd(&cursor[d], 1u);
        uint2 m;
        m.x = (unsigned)src[e];
        m.y = __float_as_uint(ew[e]);
        smeta[pos] = m;
    }
}

// ---------------- kernel 5: fp32 GEMM  h = (feat * outscale) @ wm, bf16 output ----------------
#define MT 32
#define KT 64

#define MMA_ROW(R, A)                                   \
    acc[R][0] = fmaf((A).x, b0.x, acc[R][0]);           \
    acc[R][0] = fmaf((A).y, b1.x, acc[R][0]);           \
    acc[R][0] = fmaf((A).z, b2.x, acc[R][0]);           \
    acc[R][0] = fmaf((A).w, b3.x, acc[R][0]);           \
    acc[R][1] = fmaf((A).x, b0.y, acc[R][1]);           \
    acc[R][1] = fmaf((A).y, b1.y, acc[R][1]);           \
    acc[R][1] = fmaf((A).z, b2.y, acc[R][1]);           \
    acc[R][1] = fmaf((A).w, b3.y, acc[R][1]);           \
    acc[R][2] = fmaf((A).x, b0.z, acc[R][2]);           \
    acc[R][2] = fmaf((A).y, b1.z, acc[R][2]);           \
    acc[R][2] = fmaf((A).z, b2.z, acc[R][2]);           \
    acc[R][2] = fmaf((A).w, b3.z, acc[R][2]);           \
    acc[R][3] = fmaf((A).x, b0.w, acc[R][3]);           \
    acc[R][3] = fmaf((A).y, b1.w, acc[R][3]);           \
    acc[R][3] = fmaf((A).z, b2.w, acc[R][3]);           \
    acc[R][3] = fmaf((A).w, b3.w, acc[R][3]);

__device__ __forceinline__ unsigned bf16_rne(float f) {
    unsigned u = __float_as_uint(f);
    return (u + 0x7fffu + ((u >> 16) & 1u)) >> 16;
}

__global__ __launch_bounds__(256) void gemm_kernel(const float* __restrict__ feat,
                                                   const float* __restrict__ wm,
                                                   const unsigned* __restrict__ outdeg,
                                                   unsigned* __restrict__ hrows) {
    __shared__ float sA[MT][KT];      // 8 KB
    __shared__ float sB[KT][OUT_F];   // 32 KB
    int t = threadIdx.x;
    int row0 = blockIdx.x * MT;
    int fg = (t & 31) * 4;
    int rg = (t >> 5) * 4;
    float acc[4][4] = {};

    for (int k0 = 0; k0 < IN_F; k0 += KT) {
        {
            int lr = t >> 4;
            int lc = (t & 15) * 4;
            float4 v0 = *(const float4*)&feat[(size_t)(row0 + lr) * IN_F + k0 + lc];
            float4 v1 = *(const float4*)&feat[(size_t)(row0 + lr + 16) * IN_F + k0 + lc];
            *(float4*)&sA[lr][lc] = v0;
            *(float4*)&sA[lr + 16][lc] = v1;
        }
        {
            int bk = t >> 5;
            int bf = (t & 31) * 4;
#pragma unroll
            for (int kk = 0; kk < KT; kk += 8) {
                *(float4*)&sB[bk + kk][bf] =
                    *(const float4*)&wm[(size_t)(k0 + bk + kk) * OUT_F + bf];
            }
        }
        __syncthreads();
#pragma unroll
        for (int k = 0; k < KT; k += 4) {
            float4 a0 = *(const float4*)&sA[rg + 0][k];
            float4 a1 = *(const float4*)&sA[rg + 1][k];
            float4 a2 = *(const float4*)&sA[rg + 2][k];
            float4 a3 = *(const float4*)&sA[rg + 3][k];
            float4 b0 = *(const float4*)&sB[k + 0][fg];
            float4 b1 = *(const float4*)&sB[k + 1][fg];
            float4 b2 = *(const float4*)&sB[k + 2][fg];
            float4 b3 = *(const float4*)&sB[k + 3][fg];
            MMA_ROW(0, a0)
            MMA_ROW(1, a1)
            MMA_ROW(2, a2)
            MMA_ROW(3, a3)
        }
        __syncthreads();
    }
    // scale by outdeg^-0.5, pack to bf16x2, store 8 B per row
#pragma unroll
    for (int r = 0; r < 4; r++) {
        unsigned dg = outdeg[row0 + rg + r];
        float s = rsqrtf(fmaxf((float)dg, 1.0f));
        unsigned p0 = bf16_rne(acc[r][0] * s) | (bf16_rne(acc[r][1] * s) << 16);
        unsigned p1 = bf16_rne(acc[r][2] * s) | (bf16_rne(acc[r][3] * s) << 16);
        uint2 pk = make_uint2(p0, p1);
        // row has 64 uints (128 bf16); this thread's 4 cols start at uint index fg/2
        *(uint2*)&hrows[(size_t)(row0 + rg + r) * (OUT_F / 2) + (fg >> 1)] = pk;
    }
}

// ---------------- kernel 6: CSR gather-sum, one wave per dst node ----------------
__global__ __launch_bounds__(256) void gather_kernel(const uint2* __restrict__ smeta,
                                                     const unsigned* __restrict__ offsets,
                                                     const unsigned* __restrict__ hrows,
                                                     const float* __restrict__ bias,
                                                     float* __restrict__ out) {
    int lane = threadIdx.x & 63;
    int n = blockIdx.x * 4 + (threadIdx.x >> 6);
    unsigned beg = offsets[n], end = offsets[n + 1];
    int deg = (int)(end - beg);
    float acc0 = 0.0f, acc1 = 0.0f;
    for (int base = 0; base < deg; base += 64) {
        int c = min(64, deg - base);
        unsigned sv = 0;
        float wv = 0.0f;
        if (lane < c) {
            uint2 m = smeta[beg + base + lane];
            sv = m.x;
            wv = __uint_as_float(m.y);
        }
#pragma unroll 4
        for (int i = 0; i < c; i++) {
            unsigned s = __shfl(sv, i);
            float w = __shfl(wv, i);
            unsigned hv = hrows[(size_t)s * (OUT_F / 2) + lane];
            float lo = __uint_as_float(hv << 16);
            float hi = __uint_as_float(hv & 0xffff0000u);
            acc0 = fmaf(lo, w, acc0);
            acc1 = fmaf(hi, w, acc1);
        }
    }
    float s = rsqrtf(fmaxf((float)deg, 1.0f));
    float2 b = *(const float2*)&bias[2 * lane];
    float2 o = make_float2(acc0 * s + b.x, acc1 * s + b.y);
    *(float2*)&out[(size_t)n * OUT_F + 2 * lane] = o;
}

extern "C" void kernel_launch(void* const* d_in, const int* in_sizes, int n_in,
                              void* d_out, int out_size, void* d_ws, size_t ws_size,
                              hipStream_t stream) {
    const float* feat      = (const float*)d_in[0];
    const int*   src       = (const int*)d_in[1];
    const int*   dst       = (const int*)d_in[2];
    const float* ew        = (const float*)d_in[3];
    const float* weight    = (const float*)d_in[4];
    const float* bias      = (const float*)d_in[5];
    const float* mask_real = (const float*)d_in[6];
    float* out = (float*)d_out;

    char* ws = (char*)d_ws;
    size_t o = 0;
    auto take = [&](size_t bytes) {
        char* p = ws + o;
        o = (o + bytes + 255) & ~(size_t)255;
        return p;
    };
    float*    wm     = (float*)take((size_t)IN_F * OUT_F * 4);
    unsigned* outdeg = (unsigned*)take((size_t)N_NODES * 4);
    unsigned* indeg  = (unsigned*)take((size_t)N_NODES * 4);
    unsigned* offs   = (unsigned*)take((size_t)(N_NODES + 1) * 4);
    unsigned* cursor = (unsigned*)take((size_t)N_NODES * 4);
    uint2*    smeta  = (uint2*)take((size_t)N_EDGES * 8);
    unsigned* bsum   = (unsigned*)take((size_t)SCAN_NB * 4);
    unsigned* bpref  = (unsigned*)take((size_t)SCAN_NB * 4);
    unsigned* hrows  = (unsigned*)take((size_t)N_NODES * (OUT_F / 2) * 4);

    hipMemsetAsync(outdeg, 0, (size_t)N_NODES * 4, stream);
    hipMemsetAsync(indeg, 0, (size_t)N_NODES * 4, stream);

    mask_w_kernel<<<(IN_F * OUT_F + 255) / 256, 256, 0, stream>>>(weight, mask_real, wm);
    deg_kernel<<<(N_EDGES + 255) / 256, 256, 0, stream>>>(src, dst, outdeg, indeg);
    scan_reduce<<<SCAN_NB, 256, 0, stream>>>(indeg, bsum);
    scan_spine<<<1, 512, 0, stream>>>(bsum, bpref, offs);
    scan_apply<<<SCAN_NB, 256, 0, stream>>>(indeg, bpref, offs, cursor);
    gemm_kernel<<<N_NODES / MT, 256, 0, stream>>>(feat, wm, outdeg, hrows);
    fill_kernel<<<(N_EDGES + 255) / 256, 256, 0, stream>>>(src, dst, ew, cursor, smeta);
    gather_kernel<<<N_NODES / 4, 256, 0, stream>>>(smeta, offs, hrows, bias, out);
}